// Round 18
// baseline (85.104 us; speedup 1.0000x reference)
//
#include <hip/hip_runtime.h>
#include <stdint.h>

#define EPSV 1e-5f

typedef __attribute__((ext_vector_type(4))) float f32x4;
typedef __attribute__((ext_vector_type(8))) short bf16x8;

__device__ __forceinline__ unsigned short f2bf(float x){
  union{float f; uint32_t u;} a; a.f=x;
  uint32_t r = a.u + 0x7fffu + ((a.u>>16)&1u);
  return (unsigned short)(r>>16);
}
__device__ __forceinline__ float bf2f(unsigned short u){
  union{uint32_t x; float f;} a; a.x = (uint32_t)u<<16; return a.f;
}
// raw v_exp_f32: D = 2^S0 (ISA-exact; negatives flush toward 0 — correct for softmax tails)
__device__ __forceinline__ float exp2_raw(float x){
  float r;
  asm("v_exp_f32 %0, %1" : "=v"(r) : "v"(x));
  return r;
}
// split float into bf16 hi (truncated) + bf16 lo (RNE of remainder)
__device__ __forceinline__ void split2(float x, unsigned short& h, unsigned short& l){
  union{float f; uint32_t u;} a; a.f=x;
  union{uint32_t u; float f;} b; b.u = a.u & 0xffff0000u;
  h = (unsigned short)(b.u>>16);
  l = f2bf(x - b.f);
}
__device__ __forceinline__ f32x4 mfma16(bf16x8 a, bf16x8 b, f32x4 c){
  return __builtin_amdgcn_mfma_f32_16x16x32_bf16(a, b, c, 0, 0, 0);
}
__device__ __forceinline__ f32x4 vmax4(f32x4 a, f32x4 b){
  f32x4 r; r[0]=fmaxf(a[0],b[0]); r[1]=fmaxf(a[1],b[1]);
  r[2]=fmaxf(a[2],b[2]); r[3]=fmaxf(a[3],b[3]); return r;
}
__device__ __forceinline__ void gload_lds16(const void* g, void* l){
  __builtin_amdgcn_global_load_lds(
     (const __attribute__((address_space(1))) uint32_t*)g,
     (__attribute__((address_space(3))) uint32_t*)l, 16, 0, 0);
}

#define QF 0.25503464f   /* 1/sqrt(32) * log2(e) */

// ---------------- fused prep: transpose x (blocks 0..2047) + weight split (blocks 2048..2303) ----------------
__global__ __launch_bounds__(256)
void prep_all(const float* __restrict__ x, uint16_t* __restrict__ Xth,
              const float* __restrict__ Wq,
              const float* __restrict__ gq, const float* __restrict__ bq,
              const float* __restrict__ mq, const float* __restrict__ vq,
              const float* __restrict__ Wp,
              const float* __restrict__ gp, const float* __restrict__ bp,
              const float* __restrict__ mp, const float* __restrict__ vp,
              uint16_t* __restrict__ wqh, uint16_t* __restrict__ wql, float* __restrict__ shq,
              uint16_t* __restrict__ wph, uint16_t* __restrict__ wpl, float* __restrict__ shp)
{
  __shared__ float tile[32][33];
  const int bid = blockIdx.x, t = threadIdx.x;
  if (bid < 2048){
    const int n0 = (bid & 127)*32, c0 = ((bid>>7)&7)*32, b = bid>>10;
    const float* s = x + ((size_t)b*256 + c0)*4096 + n0;
    #pragma unroll
    for (int i=0;i<4;i++){
      int idx = t + i*256; int cl = idx>>5, nl = idx&31;
      tile[cl][nl] = s[(size_t)cl*4096 + nl];
    }
    __syncthreads();
    int nl = t>>3, cg = (t&7)*4;
    uint16_t h4[4];
    #pragma unroll
    for (int k=0;k<4;k++) h4[k] = f2bf(tile[cg+k][nl]);
    size_t o = ((size_t)b*4096 + n0+nl)*256 + c0 + cg;
    *(uint2*)(Xth+o) = *(const uint2*)h4;
  } else {
    int bb = bid - 2048;
    const float *W, *gg, *bbp, *bm, *bv; uint16_t *wh, *wl; float* shift;
    int i; int mode;
    if (bb < 192){ i = bb*256 + t; W=Wq; gg=gq; bbp=bq; bm=mq; bv=vq; wh=wqh; wl=wql; shift=shq; mode=1; }
    else         { i = (bb-192)*256 + t; W=Wp; gg=gp; bbp=bp; bm=mp; bv=vp; wh=wph; wl=wpl; shift=shp; mode=0; }
    int row = i >> 6, c4 = (i & 63)*4;
    float s = gg[row]*rsqrtf(bv[row] + EPSV);
    float sh = bbp[row] - bm[row]*s;
    if (mode == 1 && (row % 96) < 32){ s *= QF; sh *= QF; }
    f32x4 v = *(const f32x4*)(W + (size_t)row*256 + c4);
    uint16_t h4[4], l4[4];
    #pragma unroll
    for (int k=0;k<4;k++) split2(v[k]*s, h4[k], l4[k]);
    size_t o = (size_t)row*256 + c4;
    *(uint2*)(wh+o) = *(const uint2*)h4;
    *(uint2*)(wl+o) = *(const uint2*)l4;
    if (c4 == 0) shift[row] = sh;
  }
}

// ---------------- prep: transpose + round [B][256][4096] f32 -> [B][4096][256] bf16 ----------------
__global__ __launch_bounds__(256)
void transpose_bf16(const float* __restrict__ src, uint16_t* __restrict__ dh)
{
  __shared__ float tile[32][33];
  const int t = threadIdx.x;
  const int n0 = blockIdx.x*32, c0 = blockIdx.y*32, b = blockIdx.z;
  const float* s = src + ((size_t)b*256 + c0)*4096 + n0;
  #pragma unroll
  for (int i=0;i<4;i++){
    int idx = t + i*256; int cl = idx>>5, nl = idx&31;
    tile[cl][nl] = s[(size_t)cl*4096 + nl];
  }
  __syncthreads();
  int nl = t>>3, cg = (t&7)*4;
  uint16_t h4[4];
  #pragma unroll
  for (int k=0;k<4;k++) h4[k] = f2bf(tile[cg+k][nl]);
  size_t o = ((size_t)b*4096 + n0+nl)*256 + c0 + cg;
  *(uint2*)(dh+o) = *(const uint2*)h4;
}

// ---------------- LDS-staged GEMM (m97 structure): Out = sum_c Wsc[o][c]*X[b][n][c] + shift ----------------
// MT = m-tile (128 or 64). Tile MT x 64n, BK=32, 4 waves, quad-XOR swizzle (conflict-free).
template<int MODE, int MT>
__global__ __launch_bounds__(256)
void gemm_lds(const uint16_t* __restrict__ Awh, const uint16_t* __restrict__ Awl,
              const float* __restrict__ shift,
              const uint16_t* __restrict__ Bxh,
              float* __restrict__ Out,
              uint16_t* __restrict__ qth, uint16_t* __restrict__ qtl,
              uint16_t* __restrict__ kth, uint16_t* __restrict__ ktl,
              uint16_t* __restrict__ vhp, int M)
{
  constexpr int NA = MT/32;
  __shared__ __align__(16) uint16_t Ah[MT*32], Al[MT*32], Bs[64*32];
  const int t = threadIdx.x, lane = t&63, wid = t>>6;
  const int g = lane>>4, li = lane&15;
  const int nb = blockIdx.x*64, mb = blockIdx.y*MT, b = blockIdx.z;

  // staging source (quad-swizzled so linear LDS dest ends up bank-spread)
  const int srow = lane>>2;                          // 0..15
  const int sq   = ((lane&3) ^ ((lane>>3)&3))*8;     // u16 units
  const uint16_t* gAh = Awh + (size_t)(mb + wid*(MT/4) + srow)*256 + sq;
  const uint16_t* gAl = Awl + (size_t)(mb + wid*(MT/4) + srow)*256 + sq;
  const uint16_t* gB  = Bxh + ((size_t)b*4096 + nb + wid*16 + srow)*256 + sq;
  uint16_t* lAh0 = &Ah[(wid*(MT/4))*32];
  uint16_t* lAl0 = &Al[(wid*(MT/4))*32];
  uint16_t* lAh1 = &Ah[(wid*(MT/4)+16)*32];
  uint16_t* lAl1 = &Al[(wid*(MT/4)+16)*32];
  uint16_t* lB0  = &Bs[(wid*16)*32];

  f32x4 acc[NA][2];
  #pragma unroll
  for (int i=0;i<NA;i++)
    #pragma unroll
    for (int j=0;j<2;j++){ f32x4 z={0.f,0.f,0.f,0.f}; acc[i][j]=z; }

  const int gq2 = (g ^ ((li>>1)&3))*8;   // swizzled read quad (per-thread constant)

  for (int ks=0; ks<8; ++ks){
    if (ks) __syncthreads();
    gload_lds16(gAh + ks*32, lAh0);
    gload_lds16(gAl + ks*32, lAl0);
    if (MT == 128){
      gload_lds16(gAh + 16*256 + ks*32, lAh1);
      gload_lds16(gAl + 16*256 + ks*32, lAl1);
    }
    gload_lds16(gB + ks*32, lB0);
    __syncthreads();

    bf16x8 ah[NA], al[NA], bh[2];
    #pragma unroll
    for (int i=0;i<NA;i++){
      int row = (wid>>1)*(MT/2) + i*16 + li;
      ah[i] = *(const bf16x8*)&Ah[row*32 + gq2];
      al[i] = *(const bf16x8*)&Al[row*32 + gq2];
    }
    #pragma unroll
    for (int j=0;j<2;j++){
      int row = (wid&1)*32 + j*16 + li;
      bh[j] = *(const bf16x8*)&Bs[row*32 + gq2];
    }
    #pragma unroll
    for (int i=0;i<NA;i++)
      #pragma unroll
      for (int j=0;j<2;j++){
        acc[i][j] = mfma16(ah[i], bh[j], acc[i][j]);
        acc[i][j] = mfma16(al[i], bh[j], acc[i][j]);
      }
  }

  const int m0 = mb + (wid>>1)*(MT/2);
  const int n00 = nb + (wid&1)*32;
  if (MODE == 0){
    #pragma unroll
    for (int i=0;i<NA;i++)
      #pragma unroll
      for (int j=0;j<2;j++){
        int orow0 = m0 + i*16 + g*4;
        int ocol  = n00 + j*16 + li;
        float* op = Out + ((size_t)b*M + orow0)*4096 + ocol;
        #pragma unroll
        for (int r=0;r<4;r++)
          op[(size_t)r*4096] = acc[i][j][r] + shift[orow0 + r];
      }
  } else {
    #pragma unroll
    for (int i=0;i<NA;i++){
      int base = m0 + i*16;            // q/k/v type uniform over these 16 rows
      int hh = base/96;
      int rem = base - hh*96;          // {0,16,32,48,64,80}
      #pragma unroll
      for (int j=0;j<2;j++){
        int ocol = n00 + j*16 + li;
        int area = ocol >> 10, mm = ocol & 1023;
        if (rem < 64){                 // q or k: split hi/lo, attention layout
          uint16_t h4[4], l4[4];
          #pragma unroll
          for (int r=0;r<4;r++){
            float val = acc[i][j][r] + shift[base + g*4 + r];
            split2(val, h4[r], l4[r]);
          }
          size_t o = (((size_t)(b*4+area)*8 + hh)*1024 + mm)*32 + (rem & 31) + g*4;
          if (rem < 32){
            *(uint2*)(qth+o) = *(const uint2*)h4;
            *(uint2*)(qtl+o) = *(const uint2*)l4;
          } else {
            *(uint2*)(kth+o) = *(const uint2*)h4;
            *(uint2*)(ktl+o) = *(const uint2*)l4;
          }
        } else {                       // v -> single bf16 plane [b*8+h][d][n]
          size_t vrow = (size_t)(b*8+hh)*32 + (rem-64) + g*4;
          #pragma unroll
          for (int r=0;r<4;r++){
            float val = acc[i][j][r] + shift[base + g*4 + r];
            vhp[(vrow + r)*4096 + ocol] = f2bf(val);
          }
        }
      }
    }
  }
}

// ---------------- split-m flash attention (K loaded on demand — smaller live set) ----------------
__global__ __launch_bounds__(64)
void attn_kernel(const uint16_t* __restrict__ qth, const uint16_t* __restrict__ qtl,
                 const uint16_t* __restrict__ kth, const uint16_t* __restrict__ ktl,
                 const uint16_t* __restrict__ vh,
                 uint16_t* __restrict__ po, float* __restrict__ pm, float* __restrict__ ps)
{
  const int lane = threadIdx.x;
  const int g = lane >> 4, li = lane & 15;
  const int bid  = blockIdx.x;           // 0..4095
  const int xcd  = bid & 7;
  const int rr   = bid >> 3;             // 0..511
  const int prob = xcd*8 + (rr >> 6);    // 0..63 — bijective
  const int sub  = rr & 63;
  const int nwv  = sub >> 1;             // 0..31
  const int mh   = sub & 1;              // key half
  const int ba = prob >> 3, h = prob & 7;
  const int b = ba >> 2, area = ba & 3;

  __shared__ __align__(16) unsigned short pt[32][72];

  const size_t qkrow = (size_t)prob*1024;
  const int nw = nwv*32;
  const int mbase = mh*512;

  bf16x8 qh[2], ql[2];
  #pragma unroll
  for (int nt=0; nt<2; nt++){
    qh[nt] = *(const bf16x8*)(qth + (qkrow + nw + nt*16 + li)*32 + g*8);
    ql[nt] = *(const bf16x8*)(qtl + (qkrow + nw + nt*16 + li)*32 + g*8);
  }

  // loop-carried per-lane pointers
  const uint16_t* kph = kth + (qkrow + mbase + (size_t)li)*32 + g*8;   // += 2048 elems/iter
  const uint16_t* kpl = ktl + (qkrow + mbase + (size_t)li)*32 + g*8;
  const uint16_t* vp  = vh + ((size_t)(b*8+h)*32 + li)*4096
                           + area*1024 + mbase + g*8;                  // += 64 elems/iter

  float mrun[2] = {-1e30f, -1e30f};      // row-uniform
  f32x4 oacc[2][2], dacc[2];
  #pragma unroll
  for (int dt=0;dt<2;dt++)
    #pragma unroll
    for (int nt=0;nt<2;nt++){ f32x4 z = {0.f,0.f,0.f,0.f}; oacc[dt][nt] = z; }
  #pragma unroll
  for (int nt=0;nt<2;nt++){ f32x4 z = {0.f,0.f,0.f,0.f}; dacc[nt] = z; }

  const short o1 = (short)0x3F80;        // bf16 1.0
  const bf16x8 ones = {o1,o1,o1,o1,o1,o1,o1,o1};

  for (int m0 = 0; m0 < 512; m0 += 64){
    // K fragments on demand (no cross-iteration double-buffer)
    bf16x8 kh[4], kl[4];
    #pragma unroll
    for (int mt=0;mt<4;mt++){
      kh[mt] = *(const bf16x8*)(kph + mt*512);
      kl[mt] = *(const bf16x8*)(kpl + mt*512);
    }
    bf16x8 vf[2][2];
    #pragma unroll
    for (int dt=0;dt<2;dt++)
      #pragma unroll
      for (int ks=0;ks<2;ks++)
        vf[dt][ks] = *(const bf16x8*)(vp + dt*16*4096 + ks*32);

    f32x4 s[4][2];
    __builtin_amdgcn_s_setprio(1);
    #pragma unroll
    for (int mt=0;mt<4;mt++)
      #pragma unroll
      for (int nt=0;nt<2;nt++){
        f32x4 z = {0.f,0.f,0.f,0.f};
        z = mfma16(kh[mt], qh[nt], z);
        z = mfma16(kl[mt], qh[nt], z);
        z = mfma16(kh[mt], ql[nt], z);
        s[mt][nt] = z;
      }
    __builtin_amdgcn_s_setprio(0);

    kph += 2048; kpl += 2048; vp += 64;

    #pragma unroll
    for (int nt=0; nt<2; nt++){
      // per-lane max over this lane's 16 m-values (no shfl)
      f32x4 m01 = vmax4(s[0][nt], s[1][nt]);
      f32x4 m23 = vmax4(s[2][nt], s[3][nt]);
      f32x4 mm4 = vmax4(m01, m23);
      float lmx = fmaxf(fmaxf(mm4[0], mm4[1]), fmaxf(mm4[2], mm4[3]));
      // defer-max trigger: VCC-reduce, free; full reduce + rescale only when needed
      if (__any(lmx > mrun[nt] + 8.0f)){
        float mx = fmaxf(lmx, __shfl_xor(lmx, 16, 64));
        mx = fmaxf(mx, __shfl_xor(mx, 32, 64));
        float mnew = fmaxf(mrun[nt], mx);
        float corr = exp2_raw(mrun[nt] - mnew);
        mrun[nt] = mnew;
        #pragma unroll
        for (int dt=0;dt<2;dt++)
          #pragma unroll
          for (int r=0;r<4;r++) oacc[dt][nt][r] *= corr;
        #pragma unroll
        for (int r=0;r<4;r++) dacc[nt][r] *= corr;
      }
      #pragma unroll
      for (int mt=0; mt<4; mt++){
        f32x4 p;
        #pragma unroll
        for (int r=0;r<4;r++) p[r] = exp2_raw(s[mt][nt][r] - mrun[nt]);
        uint32_t pk01, pk23;
        asm("v_cvt_pk_bf16_f32 %0, %1, %2" : "=v"(pk01) : "v"(p[0]), "v"(p[1]));
        asm("v_cvt_pk_bf16_f32 %0, %1, %2" : "=v"(pk23) : "v"(p[2]), "v"(p[3]));
        uint2 u; u.x = pk01; u.y = pk23;
        *(uint2*)&pt[nt*16+li][mt*16 + g*4] = u;
      }
    }

    __builtin_amdgcn_s_setprio(1);
    #pragma unroll
    for (int ks=0; ks<2; ks++){
      bf16x8 pf[2];
      #pragma unroll
      for (int nt=0; nt<2; nt++)
        pf[nt] = *(const bf16x8*)&pt[nt*16+li][ks*32 + g*8];
      #pragma unroll
      for (int dt=0; dt<2; dt++)
        #pragma unroll
        for (int nt=0; nt<2; nt++)
          oacc[dt][nt] = mfma16(vf[dt][ks], pf[nt], oacc[dt][nt]);
      #pragma unroll
      for (int nt=0; nt<2; nt++)
        dacc[nt] = mfma16(ones, pf[nt], dacc[nt]);
    }
    __builtin_amdgcn_s_setprio(0);
  }

  // epilogue: dacc holds exact per-row denominators (bf16-P-consistent)
  const size_t pr = (size_t)(prob*2 + mh);
  #pragma unroll
  for (int nt=0;nt<2;nt++){
    int nn = nw + nt*16 + li;
    #pragma unroll
    for (int dt=0;dt<2;dt++){
      #pragma unroll
      for (int r=0;r<4;r++)
        po[(pr*32 + dt*16 + g*4 + r)*1024 + nn] = f2bf(oacc[dt][nt][r]);
    }
    if (g == 0){
      pm[pr*1024 + nn] = mrun[nt];
      ps[pr*1024 + nn] = dacc[nt][0];
    }
  }
}

// ---------------- fused: flash merge of the two key-halves + depthwise 7x7 conv + BN ----------------
// 2 blocks per (c,b): each handles 32 rows (yh half); vectorized tile load
__global__ __launch_bounds__(256)
void dwconv_bn_combine(const uint16_t* __restrict__ vhp,
                       const float* __restrict__ wpe,
                       const float* __restrict__ gg, const float* __restrict__ bb,
                       const float* __restrict__ bm, const float* __restrict__ bv,
                       const uint16_t* __restrict__ po, const float* __restrict__ pm,
                       const float* __restrict__ ps,
                       float* __restrict__ obuf)
{
  const int t = threadIdx.x;
  const int c = blockIdx.x;
  const int yh = blockIdx.y;
  const int b = blockIdx.z;
  const int h = c >> 5, d = c & 31;
  const size_t srow = ((size_t)(b*8 + h)*32 + d)*4096;
  const uint16_t* sh_ = vhp + srow;
  __shared__ float tile[38*70];
  // interior: 38 rows x 8 segments of 8 u16 (cols 3..66), vectorized uint4 loads
  for (int idx = t; idx < 38*8; idx += 256){
    int row = idx >> 3, seg = idx & 7;
    int y = yh*32 + row - 3;
    float* dr = &tile[row*70 + 3 + seg*8];
    if ((unsigned)y < 64u){
      uint4 v = *(const uint4*)(sh_ + (size_t)y*64 + seg*8);
      const unsigned short* u = (const unsigned short*)&v;
      #pragma unroll
      for (int k2=0;k2<8;k2++) dr[k2] = bf2f(u[k2]);
    } else {
      #pragma unroll
      for (int k2=0;k2<8;k2++) dr[k2] = 0.f;
    }
  }
  // halo columns (x out of range -> 0): cols 0..2 and 67..69
  for (int idx = t; idx < 38*6; idx += 256){
    int row = idx / 6, c2 = idx % 6;
    int col = (c2 < 3) ? c2 : 64 + c2;   // 0,1,2, 67,68,69
    tile[row*70 + col] = 0.f;
  }
  float wreg[49];
  #pragma unroll
  for (int i=0;i<49;i++) wreg[i] = wpe[c*49 + i];
  float sc = gg[c]*rsqrtf(bv[c]+EPSV);
  float sb = bb[c] - bm[c]*sc;
  __syncthreads();
  float* dst = obuf + ((size_t)b*256 + c)*4096;
  #pragma unroll
  for (int p=0;p<8;p++){
    int pl = t + p*256;                    // 0..2047
    int yl = pl >> 6, x = pl & 63;
    float acc = 0.f;
    #pragma unroll
    for (int ky=0;ky<7;ky++)
      #pragma unroll
      for (int kx=0;kx<7;kx++)
        acc += tile[(yl+ky)*70 + x + kx] * wreg[ky*7+kx];
    int pix = (yh*32 + yl)*64 + x;
    int area = pix >> 10, mm = pix & 1023;
    int prob = (b*4 + area)*8 + h;
    size_t r0 = (size_t)(prob*2    )*1024 + mm;
    size_t r1 = (size_t)(prob*2 + 1)*1024 + mm;
    float m0 = pm[r0], m1 = pm[r1];
    float s0 = ps[r0], s1 = ps[r1];
    float mx = fmaxf(m0, m1);
    float u0 = exp2_raw(m0 - mx);
    float u1 = exp2_raw(m1 - mx);
    float den = s0*u0 + s1*u1;
    float at = (bf2f(po[((size_t)(prob*2    )*32 + d)*1024 + mm])*u0 +
                bf2f(po[((size_t)(prob*2 + 1)*32 + d)*1024 + mm])*u1) / den;
    dst[pix] = at + acc*sc + sb;
  }
}

extern "C" void kernel_launch(void* const* d_in, const int* in_sizes, int n_in,
                              void* d_out, int out_size, void* d_ws, size_t ws_size,
                              hipStream_t stream) {
  const float* x       = (const float*)d_in[0];
  const float* w_qkv   = (const float*)d_in[1];
  const float* g_qkv   = (const float*)d_in[2];
  const float* b_qkv   = (const float*)d_in[3];
  const float* m_qkv   = (const float*)d_in[4];
  const float* var_qkv = (const float*)d_in[5];
  const float* w_pe    = (const float*)d_in[6];
  const float* g_pe    = (const float*)d_in[7];
  const float* b_pe    = (const float*)d_in[8];
  const float* m_pe    = (const float*)d_in[9];
  const float* var_pe  = (const float*)d_in[10];
  const float* w_proj  = (const float*)d_in[11];
  const float* g_proj  = (const float*)d_in[12];
  const float* b_proj  = (const float*)d_in[13];
  const float* m_proj  = (const float*)d_in[14];
  const float* var_proj= (const float*)d_in[15];

  char* wsb = (char*)d_ws;
  // layout (peak ~34.3 MiB), time-disjoint aliasing noted:
  uint16_t* qth  = (uint16_t*)(wsb + 0x0000000);   // 4 MiB (gemm->attn)
  uint16_t* qtl  = (uint16_t*)(wsb + 0x0400000);   // 4 MiB
  uint16_t* kth  = (uint16_t*)(wsb + 0x0800000);   // 4 MiB (gemm->attn)
  uint16_t* ktl  = (uint16_t*)(wsb + 0x0C00000);   // 4 MiB
  uint16_t* vhp  = (uint16_t*)(wsb + 0x1000000);   // 4 MiB (gemm->dwconv)
  uint16_t* Xth  = (uint16_t*)(wsb + 0x1400000);   // 4 MiB (prep->gemm)
  uint16_t* po   = (uint16_t*)(wsb + 0x1800000);   // 8 MiB (attn->dwconv)
  float*    pm   = (float*)   (wsb + 0x2000000);   // 512 KiB
  float*    ps   = (float*)   (wsb + 0x2080000);   // 512 KiB
  uint16_t* Wqh  = (uint16_t*)(wsb + 0x2100000);   // 384 KiB
  uint16_t* Wql  = (uint16_t*)(wsb + 0x2160000);   // 384 KiB
  float*    shq  = (float*)   (wsb + 0x21C0000);   // 3 KiB
  uint16_t* Wph  = (uint16_t*)(wsb + 0x2200000);   // 128 KiB
  uint16_t* Wpl  = (uint16_t*)(wsb + 0x2220000);   // 128 KiB
  float*    shp  = (float*)   (wsb + 0x2240000);   // 1 KiB
  float*    obuf = (float*)   (wsb + 0x0000000);   // 8 MiB (dwconv->transpose, over dead qth/qtl)
  uint16_t* Oth  = (uint16_t*)(wsb + 0x0800000);   // 4 MiB (transpose->proj, over dead kth)
  float*    out  = (float*)d_out;

  // 1. fused prep: transpose+round x AND weight split (one launch)
  prep_all<<<dim3(2304), 256, 0, stream>>>(x, Xth,
      w_qkv, g_qkv, b_qkv, m_qkv, var_qkv,
      w_proj, g_proj, b_proj, m_proj, var_proj,
      Wqh, Wql, shq, Wph, Wpl, shp);
  // 2. qkv GEMM (LDS-staged, MT=64 for 6 blocks/CU)
  gemm_lds<1,64><<<dim3(64,12,2), 256, 0, stream>>>(Wqh, Wql, shq, Xth,
      nullptr, qth, qtl, kth, ktl, vhp, 768);
  // 3. attention (split-m, 3-term QK, raw v_exp_f32, K on demand)
  attn_kernel<<<dim3(4096), 64, 0, stream>>>(qth, qtl, kth, ktl, vhp, po, pm, ps);
  // 4. fused merge + dwconv + BN (row-split x2, vectorized loads)
  dwconv_bn_combine<<<dim3(256,2,2), 256, 0, stream>>>(vhp, w_pe, g_pe, b_pe, m_pe, var_pe,
      po, pm, ps, obuf);
  // 5. transpose+round obuf for proj
  transpose_bf16<<<dim3(128,8,2), 256, 0, stream>>>(obuf, Oth);
  // 6. proj GEMM (MT=64 for 2 blocks/CU)
  gemm_lds<0,64><<<dim3(64,4,2), 256, 0, stream>>>(Wph, Wpl, shp, Oth,
      out, nullptr, nullptr, nullptr, nullptr, nullptr, 256);
}

// Round 19
// 80.995 us; speedup vs baseline: 1.0507x; 1.0507x over previous
//
#include <hip/hip_runtime.h>
#include <stdint.h>

#define EPSV 1e-5f

typedef __attribute__((ext_vector_type(4))) float f32x4;
typedef __attribute__((ext_vector_type(8))) short bf16x8;

__device__ __forceinline__ unsigned short f2bf(float x){
  union{float f; uint32_t u;} a; a.f=x;
  uint32_t r = a.u + 0x7fffu + ((a.u>>16)&1u);
  return (unsigned short)(r>>16);
}
__device__ __forceinline__ float bf2f(unsigned short u){
  union{uint32_t x; float f;} a; a.x = (uint32_t)u<<16; return a.f;
}
// raw v_exp_f32: D = 2^S0 (ISA-exact; negatives flush toward 0 — correct for softmax tails)
__device__ __forceinline__ float exp2_raw(float x){
  float r;
  asm("v_exp_f32 %0, %1" : "=v"(r) : "v"(x));
  return r;
}
// split float into bf16 hi (truncated) + bf16 lo (RNE of remainder)
__device__ __forceinline__ void split2(float x, unsigned short& h, unsigned short& l){
  union{float f; uint32_t u;} a; a.f=x;
  union{uint32_t u; float f;} b; b.u = a.u & 0xffff0000u;
  h = (unsigned short)(b.u>>16);
  l = f2bf(x - b.f);
}
__device__ __forceinline__ f32x4 mfma16(bf16x8 a, bf16x8 b, f32x4 c){
  return __builtin_amdgcn_mfma_f32_16x16x32_bf16(a, b, c, 0, 0, 0);
}
__device__ __forceinline__ f32x4 vmax4(f32x4 a, f32x4 b){
  f32x4 r; r[0]=fmaxf(a[0],b[0]); r[1]=fmaxf(a[1],b[1]);
  r[2]=fmaxf(a[2],b[2]); r[3]=fmaxf(a[3],b[3]); return r;
}
__device__ __forceinline__ void gload_lds16(const void* g, void* l){
  __builtin_amdgcn_global_load_lds(
     (const __attribute__((address_space(1))) uint32_t*)g,
     (__attribute__((address_space(3))) uint32_t*)l, 16, 0, 0);
}

#define QF 0.25503464f   /* 1/sqrt(32) * log2(e) */

// ---------------- fused prep: transpose x (blocks 0..2047) + weight split (blocks 2048..2303) ----------------
__global__ __launch_bounds__(256)
void prep_all(const float* __restrict__ x, uint16_t* __restrict__ Xth,
              const float* __restrict__ Wq,
              const float* __restrict__ gq, const float* __restrict__ bq,
              const float* __restrict__ mq, const float* __restrict__ vq,
              const float* __restrict__ Wp,
              const float* __restrict__ gp, const float* __restrict__ bp,
              const float* __restrict__ mp, const float* __restrict__ vp,
              uint16_t* __restrict__ wqh, uint16_t* __restrict__ wql, float* __restrict__ shq,
              uint16_t* __restrict__ wph, uint16_t* __restrict__ wpl, float* __restrict__ shp)
{
  __shared__ float tile[32][33];
  const int bid = blockIdx.x, t = threadIdx.x;
  if (bid < 2048){
    const int n0 = (bid & 127)*32, c0 = ((bid>>7)&7)*32, b = bid>>10;
    const float* s = x + ((size_t)b*256 + c0)*4096 + n0;
    #pragma unroll
    for (int i=0;i<4;i++){
      int idx = t + i*256; int cl = idx>>5, nl = idx&31;
      tile[cl][nl] = s[(size_t)cl*4096 + nl];
    }
    __syncthreads();
    int nl = t>>3, cg = (t&7)*4;
    uint16_t h4[4];
    #pragma unroll
    for (int k=0;k<4;k++) h4[k] = f2bf(tile[cg+k][nl]);
    size_t o = ((size_t)b*4096 + n0+nl)*256 + c0 + cg;
    *(uint2*)(Xth+o) = *(const uint2*)h4;
  } else {
    int bb = bid - 2048;
    const float *W, *gg, *bbp, *bm, *bv; uint16_t *wh, *wl; float* shift;
    int i; int mode;
    if (bb < 192){ i = bb*256 + t; W=Wq; gg=gq; bbp=bq; bm=mq; bv=vq; wh=wqh; wl=wql; shift=shq; mode=1; }
    else         { i = (bb-192)*256 + t; W=Wp; gg=gp; bbp=bp; bm=mp; bv=vp; wh=wph; wl=wpl; shift=shp; mode=0; }
    int row = i >> 6, c4 = (i & 63)*4;
    float s = gg[row]*rsqrtf(bv[row] + EPSV);
    float sh = bbp[row] - bm[row]*s;
    if (mode == 1 && (row % 96) < 32){ s *= QF; sh *= QF; }
    f32x4 v = *(const f32x4*)(W + (size_t)row*256 + c4);
    uint16_t h4[4], l4[4];
    #pragma unroll
    for (int k=0;k<4;k++) split2(v[k]*s, h4[k], l4[k]);
    size_t o = (size_t)row*256 + c4;
    *(uint2*)(wh+o) = *(const uint2*)h4;
    *(uint2*)(wl+o) = *(const uint2*)l4;
    if (c4 == 0) shift[row] = sh;
  }
}

// ---------------- prep: transpose + round [B][256][4096] f32 -> [B][4096][256] bf16 ----------------
__global__ __launch_bounds__(256)
void transpose_bf16(const float* __restrict__ src, uint16_t* __restrict__ dh)
{
  __shared__ float tile[32][33];
  const int t = threadIdx.x;
  const int n0 = blockIdx.x*32, c0 = blockIdx.y*32, b = blockIdx.z;
  const float* s = src + ((size_t)b*256 + c0)*4096 + n0;
  #pragma unroll
  for (int i=0;i<4;i++){
    int idx = t + i*256; int cl = idx>>5, nl = idx&31;
    tile[cl][nl] = s[(size_t)cl*4096 + nl];
  }
  __syncthreads();
  int nl = t>>3, cg = (t&7)*4;
  uint16_t h4[4];
  #pragma unroll
  for (int k=0;k<4;k++) h4[k] = f2bf(tile[cg+k][nl]);
  size_t o = ((size_t)b*4096 + n0+nl)*256 + c0 + cg;
  *(uint2*)(dh+o) = *(const uint2*)h4;
}

// ---------------- LDS-staged GEMM (m97 structure): Out = sum_c Wsc[o][c]*X[b][n][c] + shift ----------------
// MT = m-tile (128 or 64). Tile MT x 64n, BK=32, 4 waves, quad-XOR swizzle (conflict-free).
template<int MODE, int MT>
__global__ __launch_bounds__(256)
void gemm_lds(const uint16_t* __restrict__ Awh, const uint16_t* __restrict__ Awl,
              const float* __restrict__ shift,
              const uint16_t* __restrict__ Bxh,
              float* __restrict__ Out,
              uint16_t* __restrict__ qth, uint16_t* __restrict__ qtl,
              uint16_t* __restrict__ kth, uint16_t* __restrict__ ktl,
              uint16_t* __restrict__ vhp, int M)
{
  constexpr int NA = MT/32;
  __shared__ __align__(16) uint16_t Ah[MT*32], Al[MT*32], Bs[64*32];
  const int t = threadIdx.x, lane = t&63, wid = t>>6;
  const int g = lane>>4, li = lane&15;
  const int nb = blockIdx.x*64, mb = blockIdx.y*MT, b = blockIdx.z;

  // staging source (quad-swizzled so linear LDS dest ends up bank-spread)
  const int srow = lane>>2;                          // 0..15
  const int sq   = ((lane&3) ^ ((lane>>3)&3))*8;     // u16 units
  const uint16_t* gAh = Awh + (size_t)(mb + wid*(MT/4) + srow)*256 + sq;
  const uint16_t* gAl = Awl + (size_t)(mb + wid*(MT/4) + srow)*256 + sq;
  const uint16_t* gB  = Bxh + ((size_t)b*4096 + nb + wid*16 + srow)*256 + sq;
  uint16_t* lAh0 = &Ah[(wid*(MT/4))*32];
  uint16_t* lAl0 = &Al[(wid*(MT/4))*32];
  uint16_t* lAh1 = &Ah[(wid*(MT/4)+16)*32];
  uint16_t* lAl1 = &Al[(wid*(MT/4)+16)*32];
  uint16_t* lB0  = &Bs[(wid*16)*32];

  f32x4 acc[NA][2];
  #pragma unroll
  for (int i=0;i<NA;i++)
    #pragma unroll
    for (int j=0;j<2;j++){ f32x4 z={0.f,0.f,0.f,0.f}; acc[i][j]=z; }

  const int gq2 = (g ^ ((li>>1)&3))*8;   // swizzled read quad (per-thread constant)

  for (int ks=0; ks<8; ++ks){
    if (ks) __syncthreads();
    gload_lds16(gAh + ks*32, lAh0);
    gload_lds16(gAl + ks*32, lAl0);
    if (MT == 128){
      gload_lds16(gAh + 16*256 + ks*32, lAh1);
      gload_lds16(gAl + 16*256 + ks*32, lAl1);
    }
    gload_lds16(gB + ks*32, lB0);
    __syncthreads();

    bf16x8 ah[NA], al[NA], bh[2];
    #pragma unroll
    for (int i=0;i<NA;i++){
      int row = (wid>>1)*(MT/2) + i*16 + li;
      ah[i] = *(const bf16x8*)&Ah[row*32 + gq2];
      al[i] = *(const bf16x8*)&Al[row*32 + gq2];
    }
    #pragma unroll
    for (int j=0;j<2;j++){
      int row = (wid&1)*32 + j*16 + li;
      bh[j] = *(const bf16x8*)&Bs[row*32 + gq2];
    }
    #pragma unroll
    for (int i=0;i<NA;i++)
      #pragma unroll
      for (int j=0;j<2;j++){
        acc[i][j] = mfma16(ah[i], bh[j], acc[i][j]);
        acc[i][j] = mfma16(al[i], bh[j], acc[i][j]);
      }
  }

  const int m0 = mb + (wid>>1)*(MT/2);
  const int n00 = nb + (wid&1)*32;
  if (MODE == 0){
    #pragma unroll
    for (int i=0;i<NA;i++)
      #pragma unroll
      for (int j=0;j<2;j++){
        int orow0 = m0 + i*16 + g*4;
        int ocol  = n00 + j*16 + li;
        float* op = Out + ((size_t)b*M + orow0)*4096 + ocol;
        #pragma unroll
        for (int r=0;r<4;r++)
          op[(size_t)r*4096] = acc[i][j][r] + shift[orow0 + r];
      }
  } else {
    #pragma unroll
    for (int i=0;i<NA;i++){
      int base = m0 + i*16;            // q/k/v type uniform over these 16 rows
      int hh = base/96;
      int rem = base - hh*96;          // {0,16,32,48,64,80}
      #pragma unroll
      for (int j=0;j<2;j++){
        int ocol = n00 + j*16 + li;
        int area = ocol >> 10, mm = ocol & 1023;
        if (rem < 64){                 // q or k: split hi/lo, attention layout
          uint16_t h4[4], l4[4];
          #pragma unroll
          for (int r=0;r<4;r++){
            float val = acc[i][j][r] + shift[base + g*4 + r];
            split2(val, h4[r], l4[r]);
          }
          size_t o = (((size_t)(b*4+area)*8 + hh)*1024 + mm)*32 + (rem & 31) + g*4;
          if (rem < 32){
            *(uint2*)(qth+o) = *(const uint2*)h4;
            *(uint2*)(qtl+o) = *(const uint2*)l4;
          } else {
            *(uint2*)(kth+o) = *(const uint2*)h4;
            *(uint2*)(ktl+o) = *(const uint2*)l4;
          }
        } else {                       // v -> single bf16 plane [b*8+h][d][n]
          size_t vrow = (size_t)(b*8+hh)*32 + (rem-64) + g*4;
          #pragma unroll
          for (int r=0;r<4;r++){
            float val = acc[i][j][r] + shift[base + g*4 + r];
            vhp[(vrow + r)*4096 + ocol] = f2bf(val);
          }
        }
      }
    }
  }
}

// ---------------- split-m flash attention (r17 structure: prefetched K, pointer-carried) ----------------
__global__ __launch_bounds__(64)
void attn_kernel(const uint16_t* __restrict__ qth, const uint16_t* __restrict__ qtl,
                 const uint16_t* __restrict__ kth, const uint16_t* __restrict__ ktl,
                 const uint16_t* __restrict__ vh,
                 uint16_t* __restrict__ po, float* __restrict__ pm, float* __restrict__ ps)
{
  const int lane = threadIdx.x;
  const int g = lane >> 4, li = lane & 15;
  const int bid  = blockIdx.x;           // 0..4095
  const int xcd  = bid & 7;
  const int rr   = bid >> 3;             // 0..511
  const int prob = xcd*8 + (rr >> 6);    // 0..63 — bijective
  const int sub  = rr & 63;
  const int nwv  = sub >> 1;             // 0..31
  const int mh   = sub & 1;              // key half
  const int ba = prob >> 3, h = prob & 7;
  const int b = ba >> 2, area = ba & 3;

  __shared__ __align__(16) unsigned short pt[32][72];

  const size_t qkrow = (size_t)prob*1024;
  const int nw = nwv*32;
  const int mbase = mh*512;

  bf16x8 qh[2], ql[2];
  #pragma unroll
  for (int nt=0; nt<2; nt++){
    qh[nt] = *(const bf16x8*)(qth + (qkrow + nw + nt*16 + li)*32 + g*8);
    ql[nt] = *(const bf16x8*)(qtl + (qkrow + nw + nt*16 + li)*32 + g*8);
  }

  // loop-carried per-lane pointers
  const uint16_t* kph = kth + (qkrow + mbase + (size_t)li)*32 + g*8;   // += 2048 elems/iter
  const uint16_t* kpl = ktl + (qkrow + mbase + (size_t)li)*32 + g*8;
  const uint16_t* vp  = vh + ((size_t)(b*8+h)*32 + li)*4096
                           + area*1024 + mbase + g*8;                  // += 64 elems/iter

  float mrun[2] = {-1e30f, -1e30f};      // row-uniform
  f32x4 oacc[2][2], dacc[2];
  #pragma unroll
  for (int dt=0;dt<2;dt++)
    #pragma unroll
    for (int nt=0;nt<2;nt++){ f32x4 z = {0.f,0.f,0.f,0.f}; oacc[dt][nt] = z; }
  #pragma unroll
  for (int nt=0;nt<2;nt++){ f32x4 z = {0.f,0.f,0.f,0.f}; dacc[nt] = z; }

  const short o1 = (short)0x3F80;        // bf16 1.0
  const bf16x8 ones = {o1,o1,o1,o1,o1,o1,o1,o1};

  bf16x8 kh[4], kl[4];
  #pragma unroll
  for (int mt=0;mt<4;mt++){
    kh[mt] = *(const bf16x8*)(kph + mt*512);
    kl[mt] = *(const bf16x8*)(kpl + mt*512);
  }

  for (int m0 = 0; m0 < 512; m0 += 64){
    bf16x8 vf[2][2];
    #pragma unroll
    for (int dt=0;dt<2;dt++)
      #pragma unroll
      for (int ks=0;ks<2;ks++)
        vf[dt][ks] = *(const bf16x8*)(vp + dt*16*4096 + ks*32);

    f32x4 s[4][2];
    __builtin_amdgcn_s_setprio(1);
    #pragma unroll
    for (int mt=0;mt<4;mt++)
      #pragma unroll
      for (int nt=0;nt<2;nt++){
        f32x4 z = {0.f,0.f,0.f,0.f};
        z = mfma16(kh[mt], qh[nt], z);
        z = mfma16(kl[mt], qh[nt], z);
        z = mfma16(kh[mt], ql[nt], z);
        s[mt][nt] = z;
      }
    __builtin_amdgcn_s_setprio(0);

    kph += 2048; kpl += 2048;
    if (m0 < 448){
      #pragma unroll
      for (int mt=0;mt<4;mt++){
        kh[mt] = *(const bf16x8*)(kph + mt*512);
        kl[mt] = *(const bf16x8*)(kpl + mt*512);
      }
    }
    vp += 64;

    #pragma unroll
    for (int nt=0; nt<2; nt++){
      // per-lane max over this lane's 16 m-values (no shfl)
      f32x4 m01 = vmax4(s[0][nt], s[1][nt]);
      f32x4 m23 = vmax4(s[2][nt], s[3][nt]);
      f32x4 mm4 = vmax4(m01, m23);
      float lmx = fmaxf(fmaxf(mm4[0], mm4[1]), fmaxf(mm4[2], mm4[3]));
      // defer-max trigger: VCC-reduce, free; full reduce + rescale only when needed
      if (__any(lmx > mrun[nt] + 8.0f)){
        float mx = fmaxf(lmx, __shfl_xor(lmx, 16, 64));
        mx = fmaxf(mx, __shfl_xor(mx, 32, 64));
        float mnew = fmaxf(mrun[nt], mx);
        float corr = exp2_raw(mrun[nt] - mnew);
        mrun[nt] = mnew;
        #pragma unroll
        for (int dt=0;dt<2;dt++)
          #pragma unroll
          for (int r=0;r<4;r++) oacc[dt][nt][r] *= corr;
        #pragma unroll
        for (int r=0;r<4;r++) dacc[nt][r] *= corr;
      }
      #pragma unroll
      for (int mt=0; mt<4; mt++){
        f32x4 p;
        #pragma unroll
        for (int r=0;r<4;r++) p[r] = exp2_raw(s[mt][nt][r] - mrun[nt]);
        uint32_t pk01, pk23;
        asm("v_cvt_pk_bf16_f32 %0, %1, %2" : "=v"(pk01) : "v"(p[0]), "v"(p[1]));
        asm("v_cvt_pk_bf16_f32 %0, %1, %2" : "=v"(pk23) : "v"(p[2]), "v"(p[3]));
        uint2 u; u.x = pk01; u.y = pk23;
        *(uint2*)&pt[nt*16+li][mt*16 + g*4] = u;
      }
    }

    __builtin_amdgcn_s_setprio(1);
    #pragma unroll
    for (int ks=0; ks<2; ks++){
      bf16x8 pf[2];
      #pragma unroll
      for (int nt=0; nt<2; nt++)
        pf[nt] = *(const bf16x8*)&pt[nt*16+li][ks*32 + g*8];
      #pragma unroll
      for (int dt=0; dt<2; dt++)
        #pragma unroll
        for (int nt=0; nt<2; nt++)
          oacc[dt][nt] = mfma16(vf[dt][ks], pf[nt], oacc[dt][nt]);
      #pragma unroll
      for (int nt=0; nt<2; nt++)
        dacc[nt] = mfma16(ones, pf[nt], dacc[nt]);
    }
    __builtin_amdgcn_s_setprio(0);
  }

  // epilogue: dacc holds exact per-row denominators (bf16-P-consistent)
  const size_t pr = (size_t)(prob*2 + mh);
  #pragma unroll
  for (int nt=0;nt<2;nt++){
    int nn = nw + nt*16 + li;
    #pragma unroll
    for (int dt=0;dt<2;dt++){
      #pragma unroll
      for (int r=0;r<4;r++)
        po[(pr*32 + dt*16 + g*4 + r)*1024 + nn] = f2bf(oacc[dt][nt][r]);
    }
    if (g == 0){
      pm[pr*1024 + nn] = mrun[nt];
      ps[pr*1024 + nn] = dacc[nt][0];
    }
  }
}

// ---------------- fused: flash merge of the two key-halves + depthwise 7x7 conv + BN ----------------
// 2 blocks per (c,b): each handles 32 rows (yh half); vectorized tile load
__global__ __launch_bounds__(256)
void dwconv_bn_combine(const uint16_t* __restrict__ vhp,
                       const float* __restrict__ wpe,
                       const float* __restrict__ gg, const float* __restrict__ bb,
                       const float* __restrict__ bm, const float* __restrict__ bv,
                       const uint16_t* __restrict__ po, const float* __restrict__ pm,
                       const float* __restrict__ ps,
                       float* __restrict__ obuf)
{
  const int t = threadIdx.x;
  const int c = blockIdx.x;
  const int yh = blockIdx.y;
  const int b = blockIdx.z;
  const int h = c >> 5, d = c & 31;
  const size_t srow = ((size_t)(b*8 + h)*32 + d)*4096;
  const uint16_t* sh_ = vhp + srow;
  __shared__ float tile[38*70];
  // interior: 38 rows x 8 segments of 8 u16 (cols 3..66), vectorized uint4 loads
  for (int idx = t; idx < 38*8; idx += 256){
    int row = idx >> 3, seg = idx & 7;
    int y = yh*32 + row - 3;
    float* dr = &tile[row*70 + 3 + seg*8];
    if ((unsigned)y < 64u){
      uint4 v = *(const uint4*)(sh_ + (size_t)y*64 + seg*8);
      const unsigned short* u = (const unsigned short*)&v;
      #pragma unroll
      for (int k2=0;k2<8;k2++) dr[k2] = bf2f(u[k2]);
    } else {
      #pragma unroll
      for (int k2=0;k2<8;k2++) dr[k2] = 0.f;
    }
  }
  // halo columns (x out of range -> 0): cols 0..2 and 67..69
  for (int idx = t; idx < 38*6; idx += 256){
    int row = idx / 6, c2 = idx % 6;
    int col = (c2 < 3) ? c2 : 64 + c2;   // 0,1,2, 67,68,69
    tile[row*70 + col] = 0.f;
  }
  float wreg[49];
  #pragma unroll
  for (int i=0;i<49;i++) wreg[i] = wpe[c*49 + i];
  float sc = gg[c]*rsqrtf(bv[c]+EPSV);
  float sb = bb[c] - bm[c]*sc;
  __syncthreads();
  float* dst = obuf + ((size_t)b*256 + c)*4096;
  #pragma unroll
  for (int p=0;p<8;p++){
    int pl = t + p*256;                    // 0..2047
    int yl = pl >> 6, x = pl & 63;
    float acc = 0.f;
    #pragma unroll
    for (int ky=0;ky<7;ky++)
      #pragma unroll
      for (int kx=0;kx<7;kx++)
        acc += tile[(yl+ky)*70 + x + kx] * wreg[ky*7+kx];
    int pix = (yh*32 + yl)*64 + x;
    int area = pix >> 10, mm = pix & 1023;
    int prob = (b*4 + area)*8 + h;
    size_t r0 = (size_t)(prob*2    )*1024 + mm;
    size_t r1 = (size_t)(prob*2 + 1)*1024 + mm;
    float m0 = pm[r0], m1 = pm[r1];
    float s0 = ps[r0], s1 = ps[r1];
    float mx = fmaxf(m0, m1);
    float u0 = exp2_raw(m0 - mx);
    float u1 = exp2_raw(m1 - mx);
    float den = s0*u0 + s1*u1;
    float at = (bf2f(po[((size_t)(prob*2    )*32 + d)*1024 + mm])*u0 +
                bf2f(po[((size_t)(prob*2 + 1)*32 + d)*1024 + mm])*u1) / den;
    dst[pix] = at + acc*sc + sb;
  }
}

extern "C" void kernel_launch(void* const* d_in, const int* in_sizes, int n_in,
                              void* d_out, int out_size, void* d_ws, size_t ws_size,
                              hipStream_t stream) {
  const float* x       = (const float*)d_in[0];
  const float* w_qkv   = (const float*)d_in[1];
  const float* g_qkv   = (const float*)d_in[2];
  const float* b_qkv   = (const float*)d_in[3];
  const float* m_qkv   = (const float*)d_in[4];
  const float* var_qkv = (const float*)d_in[5];
  const float* w_pe    = (const float*)d_in[6];
  const float* g_pe    = (const float*)d_in[7];
  const float* b_pe    = (const float*)d_in[8];
  const float* m_pe    = (const float*)d_in[9];
  const float* var_pe  = (const float*)d_in[10];
  const float* w_proj  = (const float*)d_in[11];
  const float* g_proj  = (const float*)d_in[12];
  const float* b_proj  = (const float*)d_in[13];
  const float* m_proj  = (const float*)d_in[14];
  const float* var_proj= (const float*)d_in[15];

  char* wsb = (char*)d_ws;
  // layout (peak ~34.3 MiB), time-disjoint aliasing noted:
  uint16_t* qth  = (uint16_t*)(wsb + 0x0000000);   // 4 MiB (gemm->attn)
  uint16_t* qtl  = (uint16_t*)(wsb + 0x0400000);   // 4 MiB
  uint16_t* kth  = (uint16_t*)(wsb + 0x0800000);   // 4 MiB (gemm->attn)
  uint16_t* ktl  = (uint16_t*)(wsb + 0x0C00000);   // 4 MiB
  uint16_t* vhp  = (uint16_t*)(wsb + 0x1000000);   // 4 MiB (gemm->dwconv)
  uint16_t* Xth  = (uint16_t*)(wsb + 0x1400000);   // 4 MiB (prep->gemm)
  uint16_t* po   = (uint16_t*)(wsb + 0x1800000);   // 8 MiB (attn->dwconv)
  float*    pm   = (float*)   (wsb + 0x2000000);   // 512 KiB
  float*    ps   = (float*)   (wsb + 0x2080000);   // 512 KiB
  uint16_t* Wqh  = (uint16_t*)(wsb + 0x2100000);   // 384 KiB
  uint16_t* Wql  = (uint16_t*)(wsb + 0x2160000);   // 384 KiB
  float*    shq  = (float*)   (wsb + 0x21C0000);   // 3 KiB
  uint16_t* Wph  = (uint16_t*)(wsb + 0x2200000);   // 128 KiB
  uint16_t* Wpl  = (uint16_t*)(wsb + 0x2220000);   // 128 KiB
  float*    shp  = (float*)   (wsb + 0x2240000);   // 1 KiB
  float*    obuf = (float*)   (wsb + 0x0000000);   // 8 MiB (dwconv->transpose, over dead qth/qtl)
  uint16_t* Oth  = (uint16_t*)(wsb + 0x0800000);   // 4 MiB (transpose->proj, over dead kth)
  float*    out  = (float*)d_out;

  // 1. fused prep: transpose+round x AND weight split (one launch)
  prep_all<<<dim3(2304), 256, 0, stream>>>(x, Xth,
      w_qkv, g_qkv, b_qkv, m_qkv, var_qkv,
      w_proj, g_proj, b_proj, m_proj, var_proj,
      Wqh, Wql, shq, Wph, Wpl, shp);
  // 2. qkv GEMM (LDS-staged, MT=64 for 6 blocks/CU)
  gemm_lds<1,64><<<dim3(64,12,2), 256, 0, stream>>>(Wqh, Wql, shq, Xth,
      nullptr, qth, qtl, kth, ktl, vhp, 768);
  // 3. attention (split-m, 3-term QK, raw v_exp_f32, prefetched K)
  attn_kernel<<<dim3(4096), 64, 0, stream>>>(qth, qtl, kth, ktl, vhp, po, pm, ps);
  // 4. fused merge + dwconv + BN (row-split x2, vectorized loads)
  dwconv_bn_combine<<<dim3(256,2,2), 256, 0, stream>>>(vhp, w_pe, g_pe, b_pe, m_pe, var_pe,
      po, pm, ps, obuf);
  // 5. transpose+round obuf for proj
  transpose_bf16<<<dim3(128,8,2), 256, 0, stream>>>(obuf, Oth);
  // 6. proj GEMM (MT=64 for 2 blocks/CU)
  gemm_lds<0,64><<<dim3(64,4,2), 256, 0, stream>>>(Wph, Wpl, shp, Oth,
      out, nullptr, nullptr, nullptr, nullptr, nullptr, 256);
}